// Round 5
// baseline (769.748 us; speedup 1.0000x reference)
//
#include <hip/hip_runtime.h>
#include <stdint.h>

#define B_ 4
#define T_ 1024
#define C_ 2048
#define H_ 32
#define HKV_ 8
#define HD_ 64
#define HID_ 5632

typedef __attribute__((ext_vector_type(8))) short short8;
typedef __attribute__((ext_vector_type(4))) float floatx4;

__device__ __forceinline__ float b2f(short s) {
  unsigned u = ((unsigned)(unsigned short)s) << 16;
  return __uint_as_float(u);
}
__device__ __forceinline__ short f2b(float f) {
  unsigned u = __float_as_uint(f);
  u = u + 0x7fffu + ((u >> 16) & 1u);
  return (short)(u >> 16);
}
__device__ __forceinline__ unsigned pk2(float a, float b) {
  return ((unsigned)(unsigned short)f2b(a)) |
         ((unsigned)(unsigned short)f2b(b) << 16);
}

// async global->LDS, 16B per lane, LDS dest = wave-uniform base + lane*16
#define GL2LDS(gp, lp)                                              \
  __builtin_amdgcn_global_load_lds(                                 \
      (const __attribute__((address_space(1))) void*)(gp),          \
      (__attribute__((address_space(3))) void*)(lp), 16, 0, 0)

// NOTE (R2 lesson): XCD-aware block swizzle REGRESSED these GEMMs
// (FETCH 283->716MB, gateup 178->218us). Default round-robin dispatch keeps
// all 8 XCDs in phase on the same weight panel, so L3 serves 7 of 8 fetches.
// NOTE (R1 lesson): naive 8-phase 256-tile port regressed (MfmaUtil 49->36,
// conflicts 1.4M->10.8M, mostly a 16-way-conflicted epilogue exchange).
// The 2-barrier 128x128 structure is the proven baseline (~1060 TF).

// ---------------- weight convert + transpose: W[K][N] fp32 -> Wt[N][K] bf16 ----
__global__ __launch_bounds__(256) void convt_kernel(
    const float* __restrict__ W, short* __restrict__ Wt, int K, int N) {
  __shared__ unsigned u[32][65];
  int n0 = blockIdx.x * 64, k0 = blockIdx.y * 64;
  int tx = threadIdx.x & 63, ty = threadIdx.x >> 6;  // ty 0..3
#pragma unroll
  for (int j = 0; j < 8; ++j) {
    int kpair = ty * 8 + j;  // 0..31
    float lo = W[(size_t)(k0 + 2 * kpair) * N + n0 + tx];
    float hi = W[(size_t)(k0 + 2 * kpair + 1) * N + n0 + tx];
    u[kpair][tx] = pk2(lo, hi);
  }
  __syncthreads();
  int ny = threadIdx.x >> 2, kx = threadIdx.x & 3;
  unsigned vals[8];
#pragma unroll
  for (int i = 0; i < 8; ++i) vals[i] = u[kx * 8 + i][ny];
  uint4* dst = (uint4*)(Wt + (size_t)(n0 + ny) * K + k0 + kx * 16);
  dst[0] = make_uint4(vals[0], vals[1], vals[2], vals[3]);
  dst[1] = make_uint4(vals[4], vals[5], vals[6], vals[7]);
}

// ---------------- v transpose: qkv v-heads [b][t][3072] -> vt[bg][d][t] ------
__global__ __launch_bounds__(256) void vt_kernel(
    const short* __restrict__ qkv, short* __restrict__ vout) {
  __shared__ short t[32][33];
  int t0 = blockIdx.x * 32, d0 = blockIdx.y * 32, bg = blockIdx.z;
  int b = bg >> 3, g = bg & 7;
  int tx = threadIdx.x & 31, ty = threadIdx.x >> 5;
  const short* src = qkv + (size_t)b * T_ * 3072 + (40 + g) * 64;
  short* dst = vout + (size_t)bg * T_ * HD_;
#pragma unroll
  for (int j = 0; j < 4; ++j)
    t[ty + j * 8][tx] = src[(size_t)(t0 + ty + j * 8) * 3072 + d0 + tx];
  __syncthreads();
#pragma unroll
  for (int j = 0; j < 4; ++j)
    dst[(size_t)(d0 + ty + j * 8) * T_ + t0 + tx] = t[tx][ty + j * 8];
}

// ---------------- RMSNorm: fp32 row -> bf16 row ----------------
__global__ __launch_bounds__(256) void rmsnorm_kernel(
    const float* __restrict__ x, const float* __restrict__ scale,
    short* __restrict__ out) {
  int row = blockIdx.x, tid = threadIdx.x;
  const float4* xr = (const float4*)(x + (size_t)row * C_);
  float4 v0 = xr[tid], v1 = xr[tid + 256];
  float s = v0.x * v0.x + v0.y * v0.y + v0.z * v0.z + v0.w * v0.w +
            v1.x * v1.x + v1.y * v1.y + v1.z * v1.z + v1.w * v1.w;
  for (int off = 32; off > 0; off >>= 1) s += __shfl_down(s, off, 64);
  __shared__ float red[4];
  if ((tid & 63) == 0) red[tid >> 6] = s;
  __syncthreads();
  float tot = red[0] + red[1] + red[2] + red[3];
  float r = rsqrtf(tot * (1.0f / (float)C_) + 1e-6f);
  const float4* sc = (const float4*)scale;
  float4 s0 = sc[tid], s1 = sc[tid + 256];
  uint2* o = (uint2*)(out + (size_t)row * C_);
  o[tid] = make_uint2(pk2(v0.x * s0.x * r, v0.y * s0.y * r),
                      pk2(v0.z * s0.z * r, v0.w * s0.w * r));
  o[tid + 256] = make_uint2(pk2(v1.x * s1.x * r, v1.y * s1.y * r),
                            pk2(v1.z * s1.z * r, v1.w * s1.w * r));
}

// ---------------- GEMM 128x128, BK=64 -----------------------------------------
template <int EPI>
__global__ __launch_bounds__(256, 2) void gemm128_kernel(
    const short* __restrict__ A, const short* __restrict__ Bt,
    void* __restrict__ Out, const float* __restrict__ resid,
    int M, int N, int K) {
  __shared__ __align__(16) short smem[16384];
  short* As = smem;
  short* Bs = smem + 8192;
  int tid = threadIdx.x, lane = tid & 63, wave = tid >> 6;
  int quad = lane >> 4, l16 = lane & 15;
  int m0 = blockIdx.y * 128, n0 = blockIdx.x * 128;
  int wm = (wave & 1) * 64, wn = (wave >> 1) * 64;

  const short* ap[4];
  const short* bp[4];
  short* lA[4];
  short* lB[4];
#pragma unroll
  for (int c = 0; c < 4; ++c) {
    int S = wave * 256 + c * 64 + lane;
    int row = S >> 3, kc = ((S & 7) - (row & 7)) & 7;
    ap[c] = A + (size_t)(m0 + row) * K + kc * 8;
    bp[c] = Bt + (size_t)(n0 + row) * K + kc * 8;
    lA[c] = As + (wave * 256 + c * 64) * 8;
    lB[c] = Bs + (wave * 256 + c * 64) * 8;
  }

  int aoff[4], boff[4];
#pragma unroll
  for (int i = 0; i < 4; ++i) {
    int ra = wm + i * 16 + l16;
    aoff[i] = (ra * 8 + ((quad + ra) & 7)) * 8;
    int rb = wn + i * 16 + l16;
    boff[i] = (rb * 8 + ((quad + rb) & 7)) * 8;
  }

  floatx4 acc[4][4] = {};
  for (int k0 = 0; k0 < K; k0 += 64) {
#pragma unroll
    for (int c = 0; c < 4; ++c) {
      GL2LDS(ap[c] + k0, lA[c]);
      GL2LDS(bp[c] + k0, lB[c]);
    }
    __syncthreads();
#pragma unroll
    for (int h = 0; h < 2; ++h) {
      short8 af[4], bf[4];
#pragma unroll
      for (int i = 0; i < 4; ++i) af[i] = *(const short8*)(As + (aoff[i] ^ (h * 32)));
#pragma unroll
      for (int i = 0; i < 4; ++i) bf[i] = *(const short8*)(Bs + (boff[i] ^ (h * 32)));
#pragma unroll
      for (int mi = 0; mi < 4; ++mi)
#pragma unroll
        for (int ni = 0; ni < 4; ++ni)
          acc[mi][ni] = __builtin_amdgcn_mfma_f32_16x16x32_bf16(
              af[mi], bf[ni], acc[mi][ni], 0, 0, 0);
    }
    __syncthreads();
  }
#pragma unroll
  for (int mi = 0; mi < 4; ++mi)
#pragma unroll
    for (int ni = 0; ni < 4; ++ni)
#pragma unroll
      for (int r = 0; r < 4; ++r) {
        int row = m0 + wm + mi * 16 + quad * 4 + r;
        int col = n0 + wn + ni * 16 + l16;
        size_t idx = (size_t)row * N + col;
        float a = acc[mi][ni][r];
        if constexpr (EPI == 0)
          ((short*)Out)[idx] = f2b(a);
        else
          ((float*)Out)[idx] = resid[idx] + a;
      }
}

// ---------------- fused gate+up GEMM (BK=64), lane-local silu fusion ----------
// Each wave computes BOTH gate and up for the SAME 64x32 output tile
// (acc_g[4][2] + acc_u[4][2]), so silu(g)*u is pure register math: no LDS
// exchange, no extra barrier, no idle waves, no epilogue bank conflicts.
// Staging and per-K-step MFMA/ds_read counts identical to the proven kernel.
__global__ __launch_bounds__(256, 2) void gateup_kernel(
    const short* __restrict__ A, const short* __restrict__ Wg,
    const short* __restrict__ Wu, short* __restrict__ act, int K) {
  __shared__ __align__(16) short smem[16384];
  short* As = smem;
  short* Bs = smem + 8192;
  int tid = threadIdx.x, lane = tid & 63, wave = tid >> 6;
  int quad = lane >> 4, l16 = lane & 15;
  int m0 = blockIdx.y * 128, n0 = blockIdx.x * 64;
  int wm = (wave & 1) * 64, wc = wave >> 1;  // wc in {0,1}: 32-col half
  int half_stage = wave >> 1;

  const short* ap[4];
  const short* bp[4];
  short* lA[4];
  short* lB[4];
  const short* Bsel = half_stage ? Wu : Wg;  // LDS B rows 0-63=gate, 64-127=up
#pragma unroll
  for (int c = 0; c < 4; ++c) {
    int S = wave * 256 + c * 64 + lane;
    int row = S >> 3, kc = ((S & 7) - (row & 7)) & 7;
    ap[c] = A + (size_t)(m0 + row) * K + kc * 8;
    bp[c] = Bsel + (size_t)(n0 + row - half_stage * 64) * K + kc * 8;
    lA[c] = As + (wave * 256 + c * 64) * 8;
    lB[c] = Bs + (wave * 256 + c * 64) * 8;
  }

  int aoff[4], bgoff[2], buoff[2];
#pragma unroll
  for (int i = 0; i < 4; ++i) {
    int ra = wm + i * 16 + l16;
    aoff[i] = (ra * 8 + ((quad + ra) & 7)) * 8;
  }
#pragma unroll
  for (int i = 0; i < 2; ++i) {
    int rg = wc * 32 + i * 16 + l16;        // gate rows 0..63
    bgoff[i] = (rg * 8 + ((quad + rg) & 7)) * 8;
    int ru = 64 + rg;                       // up rows 64..127
    buoff[i] = (ru * 8 + ((quad + ru) & 7)) * 8;
  }

  floatx4 accg[4][2] = {}, accu[4][2] = {};
  for (int k0 = 0; k0 < K; k0 += 64) {
#pragma unroll
    for (int c = 0; c < 4; ++c) {
      GL2LDS(ap[c] + k0, lA[c]);
      GL2LDS(bp[c] + k0, lB[c]);
    }
    __syncthreads();
#pragma unroll
    for (int h = 0; h < 2; ++h) {
      short8 af[4], bg[2], bu[2];
#pragma unroll
      for (int i = 0; i < 4; ++i) af[i] = *(const short8*)(As + (aoff[i] ^ (h * 32)));
#pragma unroll
      for (int i = 0; i < 2; ++i) {
        bg[i] = *(const short8*)(Bs + (bgoff[i] ^ (h * 32)));
        bu[i] = *(const short8*)(Bs + (buoff[i] ^ (h * 32)));
      }
#pragma unroll
      for (int mi = 0; mi < 4; ++mi)
#pragma unroll
        for (int ni = 0; ni < 2; ++ni) {
          accg[mi][ni] = __builtin_amdgcn_mfma_f32_16x16x32_bf16(
              af[mi], bg[ni], accg[mi][ni], 0, 0, 0);
          accu[mi][ni] = __builtin_amdgcn_mfma_f32_16x16x32_bf16(
              af[mi], bu[ni], accu[mi][ni], 0, 0, 0);
        }
    }
    __syncthreads();
  }
  // lane-local epilogue: silu(g)*u, direct store
#pragma unroll
  for (int mi = 0; mi < 4; ++mi)
#pragma unroll
    for (int ni = 0; ni < 2; ++ni)
#pragma unroll
      for (int r = 0; r < 4; ++r) {
        float g = accg[mi][ni][r];
        float u = accu[mi][ni][r];
        float a = g / (1.0f + __expf(-g)) * u;
        act[(size_t)(m0 + wm + mi * 16 + quad * 4 + r) * HID_ + n0 +
            wc * 32 + ni * 16 + l16] = f2b(a);
      }
}

// ---------------- RoPE + QKV split, vectorized (16B loads/stores) -------------
__global__ __launch_bounds__(256) void rope2_kernel(
    const short* __restrict__ qkv, const float* __restrict__ cosp,
    const float* __restrict__ sinp, short* __restrict__ q,
    short* __restrict__ k) {
  int idx = blockIdx.x * 256 + threadIdx.x;  // 4*40*1024*4 = 655360 threads
  int oct = idx & 3;
  int tmp = idx >> 2;
  int t = tmp & 1023;
  int tmp2 = tmp >> 10;  // b*40 + head
  int head = tmp2 % 40;
  int b = tmp2 / 40;
  const short* src = qkv + (size_t)(b * T_ + t) * 3072 + head * 64 + oct * 16;
  short8 v0 = *(const short8*)(src);
  short8 v1 = *(const short8*)(src + 8);
  const float4* cp = (const float4*)(cosp + t * 32 + oct * 8);
  const float4* sp = (const float4*)(sinp + t * 32 + oct * 8);
  float4 c0 = cp[0], c1 = cp[1];
  float4 s0 = sp[0], s1 = sp[1];
  float sc = head < 32 ? 0.125f : 1.0f;
  float cc[8] = {c0.x, c0.y, c0.z, c0.w, c1.x, c1.y, c1.z, c1.w};
  float ss[8] = {s0.x, s0.y, s0.z, s0.w, s1.x, s1.y, s1.z, s1.w};
  unsigned w[8];
#pragma unroll
  for (int p = 0; p < 8; ++p) {
    float e = b2f(p < 4 ? v0[2 * p] : v1[2 * (p - 4)]);
    float o = b2f(p < 4 ? v0[2 * p + 1] : v1[2 * (p - 4) + 1]);
    w[p] = pk2((e * cc[p] - o * ss[p]) * sc, (e * ss[p] + o * cc[p]) * sc);
  }
  short* dst = (head < 32)
      ? q + ((size_t)(b * 32 + head) * 1024 + t) * 64 + oct * 16
      : k + ((size_t)(b * 8 + head - 32) * 1024 + t) * 64 + oct * 16;
  ((uint4*)dst)[0] = make_uint4(w[0], w[1], w[2], w[3]);
  ((uint4*)dst)[1] = make_uint4(w[4], w[5], w[6], w[7]);
}

// ---------------- Flash attention (GQA, causal), S^T/O^T formulation ----------
// T13 defer-max + T5 setprio. Max/sum reductions tree-associated to cut the
// serial VALU chain between the QK and PV MFMA clusters (16 deep -> ~5).
__global__ __launch_bounds__(256) void attn_kernel(
    const short* __restrict__ q, const short* __restrict__ k,
    const short* __restrict__ vt, short* __restrict__ y) {
  __shared__ __align__(16) short P[4][1024];  // per-wave 16 q x 64 key bf16
  int bx = blockIdx.x, h = blockIdx.y, b = blockIdx.z;
  int lane = threadIdx.x & 63, wave = threadIdx.x >> 6;
  int quad = lane >> 4, l16 = lane & 15;
  int g = h >> 2;
  const short* qp = q + (size_t)(b * H_ + h) * T_ * HD_;
  const short* kp = k + (size_t)(b * HKV_ + g) * T_ * HD_;
  const short* vp = vt + (size_t)(b * HKV_ + g) * T_ * HD_;  // [d][t]
  short* Pw = &P[wave][0];
  int sw = (l16 & 7) << 1;  // even xor keeps b128 pairing + 16B alignment
#pragma unroll 1
  for (int half = 0; half < 2; ++half) {
    int tb = half ? (15 - bx) : bx;
    int q0w = tb * 64 + wave * 16;
    int qidx = q0w + l16;
    short8 qf0 = *(const short8*)(qp + (size_t)(q0w + l16) * HD_ + quad * 8);
    short8 qf1 = *(const short8*)(qp + (size_t)(q0w + l16) * HD_ + 32 + quad * 8);
    floatx4 acc[4] = {};
    float m = -1e30f, l = 0.f;
    for (int k0 = 0; k0 <= q0w; k0 += 64) {
      floatx4 st[4];
      __builtin_amdgcn_s_setprio(1);
#pragma unroll
      for (int kt = 0; kt < 4; ++kt) {
        floatx4 z = {0.f, 0.f, 0.f, 0.f};
        const short* kb = kp + (size_t)(k0 + kt * 16 + l16) * HD_;
        short8 kf0 = *(const short8*)(kb + quad * 8);
        short8 kf1 = *(const short8*)(kb + 32 + quad * 8);
        z = __builtin_amdgcn_mfma_f32_16x16x32_bf16(kf0, qf0, z, 0, 0, 0);
        z = __builtin_amdgcn_mfma_f32_16x16x32_bf16(kf1, qf1, z, 0, 0, 0);
        st[kt] = z;
      }
      __builtin_amdgcn_s_setprio(0);
      if (k0 + 64 > q0w) {  // only the diagonal iteration needs the causal mask
#pragma unroll
        for (int kt = 0; kt < 4; ++kt)
#pragma unroll
          for (int r = 0; r < 4; ++r)
            if (k0 + kt * 16 + quad * 4 + r > qidx) st[kt][r] = -1e30f;
      }
      float mk[4];
#pragma unroll
      for (int kt = 0; kt < 4; ++kt)
        mk[kt] = fmaxf(fmaxf(st[kt][0], st[kt][1]),
                       fmaxf(st[kt][2], st[kt][3]));
      float mloc = fmaxf(fmaxf(mk[0], mk[1]), fmaxf(mk[2], mk[3]));
      mloc = fmaxf(mloc, __shfl_xor(mloc, 16, 64));
      mloc = fmaxf(mloc, __shfl_xor(mloc, 32, 64));
      if (!__all(mloc <= m + 8.0f)) {  // T13: rescale only on real max growth
        float mn = fmaxf(m, mloc);
        float alpha = __expf(m - mn);
        m = mn;
        l *= alpha;
#pragma unroll
        for (int mt = 0; mt < 4; ++mt)
#pragma unroll
          for (int r = 0; r < 4; ++r) acc[mt][r] *= alpha;
      }
      float sk[4];
#pragma unroll
      for (int kt = 0; kt < 4; ++kt) {
        float p0 = __expf(st[kt][0] - m);
        float p1 = __expf(st[kt][1] - m);
        float p2 = __expf(st[kt][2] - m);
        float p3 = __expf(st[kt][3] - m);
        st[kt][0] = p0; st[kt][1] = p1; st[kt][2] = p2; st[kt][3] = p3;
        sk[kt] = (p0 + p1) + (p2 + p3);
      }
      float rsum = (sk[0] + sk[1]) + (sk[2] + sk[3]);
      rsum += __shfl_xor(rsum, 16, 64);
      rsum += __shfl_xor(rsum, 32, 64);
      l += rsum;
      // P^T -> LDS as P[q][key], 4 consecutive keys packed per b64 write
#pragma unroll
      for (int kt = 0; kt < 4; ++kt) {
        int hc = (kt * 4 + quad) ^ sw;
        *(uint2*)(Pw + l16 * 64 + hc * 4) =
            make_uint2(pk2(st[kt][0], st[kt][1]), pk2(st[kt][2], st[kt][3]));
      }
      __builtin_amdgcn_s_setprio(1);
#pragma unroll
      for (int chunk = 0; chunk < 2; ++chunk) {
        int hc = (chunk * 8 + quad * 2) ^ sw;
        short8 pf = *(const short8*)(Pw + l16 * 64 + hc * 4);
#pragma unroll
        for (int mt = 0; mt < 4; ++mt) {
          short8 vf = *(const short8*)(vp + (size_t)(mt * 16 + l16) * T_ +
                                       k0 + chunk * 32 + quad * 8);
          acc[mt] =
              __builtin_amdgcn_mfma_f32_16x16x32_bf16(vf, pf, acc[mt], 0, 0, 0);
        }
      }
      __builtin_amdgcn_s_setprio(0);
    }
    // epilogue: O^T/l -> LDS transpose (wave-private) -> coalesced 16B stores
    float inv = 1.0f / l;
#pragma unroll
    for (int mt = 0; mt < 4; ++mt) {
      int hc = (mt * 4 + quad) ^ sw;  // d chunk = mt*16 + quad*4
      *(uint2*)(Pw + l16 * 64 + hc * 4) =
          make_uint2(pk2(acc[mt][0] * inv, acc[mt][1] * inv),
                     pk2(acc[mt][2] * inv, acc[mt][3] * inv));
    }
    uint2 o0 = *(uint2*)(Pw + l16 * 64 + (((quad * 4 + 0) ^ sw) * 4));
    uint2 o1 = *(uint2*)(Pw + l16 * 64 + (((quad * 4 + 1) ^ sw) * 4));
    uint2 o2 = *(uint2*)(Pw + l16 * 64 + (((quad * 4 + 2) ^ sw) * 4));
    uint2 o3 = *(uint2*)(Pw + l16 * 64 + (((quad * 4 + 3) ^ sw) * 4));
    uint4* dst =
        (uint4*)(y + (size_t)(b * T_ + q0w + l16) * C_ + h * 64 + quad * 16);
    dst[0] = make_uint4(o0.x, o0.y, o1.x, o1.y);
    dst[1] = make_uint4(o2.x, o2.y, o3.x, o3.y);
  }
}

extern "C" void kernel_launch(void* const* d_in, const int* in_sizes, int n_in,
                              void* d_out, int out_size, void* d_ws, size_t ws_size,
                              hipStream_t stream) {
  const float* x = (const float*)d_in[0];
  const float* cosp = (const float*)d_in[1];
  const float* sinp = (const float*)d_in[2];
  const float* w_attn = (const float*)d_in[3];
  const float* w_proj = (const float*)d_in[4];
  const float* w_gate = (const float*)d_in[5];
  const float* w_up = (const float*)d_in[6];
  const float* w_down = (const float*)d_in[7];
  const float* scale1 = (const float*)d_in[8];
  const float* scale2 = (const float*)d_in[9];
  float* out = (float*)d_out;
  char* ws = (char*)d_ws;

  // workspace layout (bytes), peak 113,246,208:
  short* S1 = (short*)(ws + 0);            // 23,068,672  wt_gate -> wt_down
  short* S2 = (short*)(ws + 23068672);     // 23,068,672  wt_up
  short* hbuf = (short*)(ws + 46137344);   // 16,777,216  h -> q -> h2
  short* S0 = (short*)(ws + 62914560);     // 12,582,912  wt_attn -> wt_proj
  short* qkv = (short*)(ws + 75497472);    // 25,165,824  qkv -> y
  short* kbuf = (short*)(ws + 100663296);  //  4,194,304
  short* vtbuf = (short*)(ws + 109051904); //  4,194,304  v transposed [bg][d][t]
  short* act = (short*)(ws + 62914560);    // 46,137,344  over S0+qkv+k (dead)

  convt_kernel<<<dim3(3072 / 64, 2048 / 64), 256, 0, stream>>>(w_attn, S0, 2048, 3072);
  rmsnorm_kernel<<<4096, 256, 0, stream>>>(x, scale1, hbuf);
  gemm128_kernel<0><<<dim3(3072 / 128, 4096 / 128), 256, 0, stream>>>(
      hbuf, S0, qkv, nullptr, 4096, 3072, 2048);
  rope2_kernel<<<2560, 256, 0, stream>>>(qkv, cosp, sinp, hbuf, kbuf);
  vt_kernel<<<dim3(32, 2, 32), 256, 0, stream>>>(qkv, vtbuf);
  attn_kernel<<<dim3(8, 32, 4), 256, 0, stream>>>(hbuf, kbuf, vtbuf, qkv);
  convt_kernel<<<dim3(2048 / 64, 2048 / 64), 256, 0, stream>>>(w_proj, S0, 2048, 2048);
  gemm128_kernel<1><<<dim3(2048 / 128, 4096 / 128), 256, 0, stream>>>(
      qkv, S0, out, x, 4096, 2048, 2048);
  rmsnorm_kernel<<<4096, 256, 0, stream>>>(out, scale2, hbuf);
  convt_kernel<<<dim3(5632 / 64, 2048 / 64), 256, 0, stream>>>(w_gate, S1, 2048, 5632);
  convt_kernel<<<dim3(5632 / 64, 2048 / 64), 256, 0, stream>>>(w_up, S2, 2048, 5632);
  gateup_kernel<<<dim3(5632 / 64, 4096 / 128), 256, 0, stream>>>(hbuf, S1, S2, act, 2048);
  convt_kernel<<<dim3(2048 / 64, 5632 / 64), 256, 0, stream>>>(w_down, S1, 5632, 2048);
  gemm128_kernel<1><<<dim3(2048 / 128, 4096 / 128), 256, 0, stream>>>(
      act, S1, out, out, 4096, 2048, 5632);
}

// Round 6
// 729.977 us; speedup vs baseline: 1.0545x; 1.0545x over previous
//
#include <hip/hip_runtime.h>
#include <stdint.h>

#define B_ 4
#define T_ 1024
#define C_ 2048
#define H_ 32
#define HKV_ 8
#define HD_ 64
#define HID_ 5632

typedef __attribute__((ext_vector_type(8))) short short8;
typedef __attribute__((ext_vector_type(4))) float floatx4;

__device__ __forceinline__ float b2f(short s) {
  unsigned u = ((unsigned)(unsigned short)s) << 16;
  return __uint_as_float(u);
}
__device__ __forceinline__ short f2b(float f) {
  unsigned u = __float_as_uint(f);
  u = u + 0x7fffu + ((u >> 16) & 1u);
  return (short)(u >> 16);
}
__device__ __forceinline__ unsigned pk2(float a, float b) {
  return ((unsigned)(unsigned short)f2b(a)) |
         ((unsigned)(unsigned short)f2b(b) << 16);
}

// async global->LDS, 16B per lane, LDS dest = wave-uniform base + lane*16
#define GL2LDS(gp, lp)                                              \
  __builtin_amdgcn_global_load_lds(                                 \
      (const __attribute__((address_space(1))) void*)(gp),          \
      (__attribute__((address_space(3))) void*)(lp), 16, 0, 0)

// NOTE (R2 lesson): XCD-aware block swizzle REGRESSED these GEMMs
// (FETCH 283->716MB). Default round-robin dispatch keeps all 8 XCDs in phase
// on the same weight panel, so L3 serves 7 of 8 fetches. Do not add T1.
// NOTE (R1 lesson): naive 8-phase 256-tile port regressed. 2-barrier 128x128
// is the proven baseline (~1050 TF, MfmaUtil 51, 0 conflicts).
// NOTE (R5 win): lane-local gate/up fusion removed the epilogue LDS exchange
// (conflicts 1.44M -> 0).

// ---------------- shared convt body: W[K][N] fp32 -> Wt[N][K] bf16 ------------
__device__ __forceinline__ void convt_body(const float* __restrict__ W,
                                           short* __restrict__ Wt, int K, int N,
                                           int n0, int k0) {
  __shared__ unsigned u[32][65];
  int tx = threadIdx.x & 63, ty = threadIdx.x >> 6;  // ty 0..3
#pragma unroll
  for (int j = 0; j < 8; ++j) {
    int kpair = ty * 8 + j;  // 0..31
    float lo = W[(size_t)(k0 + 2 * kpair) * N + n0 + tx];
    float hi = W[(size_t)(k0 + 2 * kpair + 1) * N + n0 + tx];
    u[kpair][tx] = pk2(lo, hi);
  }
  __syncthreads();
  int ny = threadIdx.x >> 2, kx = threadIdx.x & 3;
  unsigned vals[8];
#pragma unroll
  for (int i = 0; i < 8; ++i) vals[i] = u[kx * 8 + i][ny];
  uint4* dst = (uint4*)(Wt + (size_t)(n0 + ny) * K + k0 + kx * 16);
  dst[0] = make_uint4(vals[0], vals[1], vals[2], vals[3]);
  dst[1] = make_uint4(vals[4], vals[5], vals[6], vals[7]);
}

// ---------------- batched convt: w_attn + w_gate + w_up (distinct dests) ------
// Per-job block order identical to the original separate launches.
__global__ __launch_bounds__(256) void convt3_kernel(
    const float* __restrict__ w_attn, const float* __restrict__ w_gate,
    const float* __restrict__ w_up, short* __restrict__ S0,
    short* __restrict__ S1, short* __restrict__ S2) {
  int lid = blockIdx.x;
  const float* W;
  short* Wt;
  int K, N, nx;
  if (lid < 1536) {
    W = w_attn; Wt = S0; K = 2048; N = 3072; nx = 48;
  } else if (lid < 1536 + 2816) {
    lid -= 1536;
    W = w_gate; Wt = S1; K = 2048; N = 5632; nx = 88;
  } else {
    lid -= 4352;
    W = w_up; Wt = S2; K = 2048; N = 5632; nx = 88;
  }
  convt_body(W, Wt, K, N, (lid % nx) * 64, (lid / nx) * 64);
}

// ---------------- single convt (w_down -> S1, after gateup frees S1) ----------
__global__ __launch_bounds__(256) void convt_kernel(
    const float* __restrict__ W, short* __restrict__ Wt, int K, int N) {
  convt_body(W, Wt, K, N, blockIdx.x * 64, blockIdx.y * 64);
}

// ---------------- RMSNorm: fp32 row -> bf16 row ----------------
__global__ __launch_bounds__(256) void rmsnorm_kernel(
    const float* __restrict__ x, const float* __restrict__ scale,
    short* __restrict__ out) {
  int row = blockIdx.x, tid = threadIdx.x;
  const float4* xr = (const float4*)(x + (size_t)row * C_);
  float4 v0 = xr[tid], v1 = xr[tid + 256];
  float s = v0.x * v0.x + v0.y * v0.y + v0.z * v0.z + v0.w * v0.w +
            v1.x * v1.x + v1.y * v1.y + v1.z * v1.z + v1.w * v1.w;
  for (int off = 32; off > 0; off >>= 1) s += __shfl_down(s, off, 64);
  __shared__ float red[4];
  if ((tid & 63) == 0) red[tid >> 6] = s;
  __syncthreads();
  float tot = red[0] + red[1] + red[2] + red[3];
  float r = rsqrtf(tot * (1.0f / (float)C_) + 1e-6f);
  const float4* sc = (const float4*)scale;
  float4 s0 = sc[tid], s1 = sc[tid + 256];
  uint2* o = (uint2*)(out + (size_t)row * C_);
  o[tid] = make_uint2(pk2(v0.x * s0.x * r, v0.y * s0.y * r),
                      pk2(v0.z * s0.z * r, v0.w * s0.w * r));
  o[tid + 256] = make_uint2(pk2(v1.x * s1.x * r, v1.y * s1.y * r),
                            pk2(v1.z * s1.z * r, v1.w * s1.w * r));
}

// ---------------- GEMM 128x128, BK=64 -----------------------------------------
template <int EPI>
__global__ __launch_bounds__(256, 2) void gemm128_kernel(
    const short* __restrict__ A, const short* __restrict__ Bt,
    void* __restrict__ Out, const float* __restrict__ resid,
    int M, int N, int K) {
  __shared__ __align__(16) short smem[16384];
  short* As = smem;
  short* Bs = smem + 8192;
  int tid = threadIdx.x, lane = tid & 63, wave = tid >> 6;
  int quad = lane >> 4, l16 = lane & 15;
  int m0 = blockIdx.y * 128, n0 = blockIdx.x * 128;
  int wm = (wave & 1) * 64, wn = (wave >> 1) * 64;

  const short* ap[4];
  const short* bp[4];
  short* lA[4];
  short* lB[4];
#pragma unroll
  for (int c = 0; c < 4; ++c) {
    int S = wave * 256 + c * 64 + lane;
    int row = S >> 3, kc = ((S & 7) - (row & 7)) & 7;
    ap[c] = A + (size_t)(m0 + row) * K + kc * 8;
    bp[c] = Bt + (size_t)(n0 + row) * K + kc * 8;
    lA[c] = As + (wave * 256 + c * 64) * 8;
    lB[c] = Bs + (wave * 256 + c * 64) * 8;
  }

  int aoff[4], boff[4];
#pragma unroll
  for (int i = 0; i < 4; ++i) {
    int ra = wm + i * 16 + l16;
    aoff[i] = (ra * 8 + ((quad + ra) & 7)) * 8;
    int rb = wn + i * 16 + l16;
    boff[i] = (rb * 8 + ((quad + rb) & 7)) * 8;
  }

  floatx4 acc[4][4] = {};
  for (int k0 = 0; k0 < K; k0 += 64) {
#pragma unroll
    for (int c = 0; c < 4; ++c) {
      GL2LDS(ap[c] + k0, lA[c]);
      GL2LDS(bp[c] + k0, lB[c]);
    }
    __syncthreads();
#pragma unroll
    for (int h = 0; h < 2; ++h) {
      short8 af[4], bf[4];
#pragma unroll
      for (int i = 0; i < 4; ++i) af[i] = *(const short8*)(As + (aoff[i] ^ (h * 32)));
#pragma unroll
      for (int i = 0; i < 4; ++i) bf[i] = *(const short8*)(Bs + (boff[i] ^ (h * 32)));
#pragma unroll
      for (int mi = 0; mi < 4; ++mi)
#pragma unroll
        for (int ni = 0; ni < 4; ++ni)
          acc[mi][ni] = __builtin_amdgcn_mfma_f32_16x16x32_bf16(
              af[mi], bf[ni], acc[mi][ni], 0, 0, 0);
    }
    __syncthreads();
  }
#pragma unroll
  for (int mi = 0; mi < 4; ++mi)
#pragma unroll
    for (int ni = 0; ni < 4; ++ni)
#pragma unroll
      for (int r = 0; r < 4; ++r) {
        int row = m0 + wm + mi * 16 + quad * 4 + r;
        int col = n0 + wn + ni * 16 + l16;
        size_t idx = (size_t)row * N + col;
        float a = acc[mi][ni][r];
        if constexpr (EPI == 0)
          ((short*)Out)[idx] = f2b(a);
        else
          ((float*)Out)[idx] = resid[idx] + a;
      }
}

// ---------------- fused gate+up GEMM (BK=64), lane-local silu fusion ----------
__global__ __launch_bounds__(256, 2) void gateup_kernel(
    const short* __restrict__ A, const short* __restrict__ Wg,
    const short* __restrict__ Wu, short* __restrict__ act, int K) {
  __shared__ __align__(16) short smem[16384];
  short* As = smem;
  short* Bs = smem + 8192;
  int tid = threadIdx.x, lane = tid & 63, wave = tid >> 6;
  int quad = lane >> 4, l16 = lane & 15;
  int m0 = blockIdx.y * 128, n0 = blockIdx.x * 64;
  int wm = (wave & 1) * 64, wc = wave >> 1;  // wc in {0,1}: 32-col half
  int half_stage = wave >> 1;

  const short* ap[4];
  const short* bp[4];
  short* lA[4];
  short* lB[4];
  const short* Bsel = half_stage ? Wu : Wg;  // LDS B rows 0-63=gate, 64-127=up
#pragma unroll
  for (int c = 0; c < 4; ++c) {
    int S = wave * 256 + c * 64 + lane;
    int row = S >> 3, kc = ((S & 7) - (row & 7)) & 7;
    ap[c] = A + (size_t)(m0 + row) * K + kc * 8;
    bp[c] = Bsel + (size_t)(n0 + row - half_stage * 64) * K + kc * 8;
    lA[c] = As + (wave * 256 + c * 64) * 8;
    lB[c] = Bs + (wave * 256 + c * 64) * 8;
  }

  int aoff[4], bgoff[2], buoff[2];
#pragma unroll
  for (int i = 0; i < 4; ++i) {
    int ra = wm + i * 16 + l16;
    aoff[i] = (ra * 8 + ((quad + ra) & 7)) * 8;
  }
#pragma unroll
  for (int i = 0; i < 2; ++i) {
    int rg = wc * 32 + i * 16 + l16;        // gate rows 0..63
    bgoff[i] = (rg * 8 + ((quad + rg) & 7)) * 8;
    int ru = 64 + rg;                       // up rows 64..127
    buoff[i] = (ru * 8 + ((quad + ru) & 7)) * 8;
  }

  floatx4 accg[4][2] = {}, accu[4][2] = {};
  for (int k0 = 0; k0 < K; k0 += 64) {
#pragma unroll
    for (int c = 0; c < 4; ++c) {
      GL2LDS(ap[c] + k0, lA[c]);
      GL2LDS(bp[c] + k0, lB[c]);
    }
    __syncthreads();
#pragma unroll
    for (int h = 0; h < 2; ++h) {
      short8 af[4], bg[2], bu[2];
#pragma unroll
      for (int i = 0; i < 4; ++i) af[i] = *(const short8*)(As + (aoff[i] ^ (h * 32)));
#pragma unroll
      for (int i = 0; i < 2; ++i) {
        bg[i] = *(const short8*)(Bs + (bgoff[i] ^ (h * 32)));
        bu[i] = *(const short8*)(Bs + (buoff[i] ^ (h * 32)));
      }
#pragma unroll
      for (int mi = 0; mi < 4; ++mi)
#pragma unroll
        for (int ni = 0; ni < 2; ++ni) {
          accg[mi][ni] = __builtin_amdgcn_mfma_f32_16x16x32_bf16(
              af[mi], bg[ni], accg[mi][ni], 0, 0, 0);
          accu[mi][ni] = __builtin_amdgcn_mfma_f32_16x16x32_bf16(
              af[mi], bu[ni], accu[mi][ni], 0, 0, 0);
        }
    }
    __syncthreads();
  }
  // lane-local epilogue: silu(g)*u, direct store
#pragma unroll
  for (int mi = 0; mi < 4; ++mi)
#pragma unroll
    for (int ni = 0; ni < 2; ++ni)
#pragma unroll
      for (int r = 0; r < 4; ++r) {
        float g = accg[mi][ni][r];
        float u = accu[mi][ni][r];
        float a = g / (1.0f + __expf(-g)) * u;
        act[(size_t)(m0 + wm + mi * 16 + quad * 4 + r) * HID_ + n0 +
            wc * 32 + ni * 16 + l16] = f2b(a);
      }
}

// ---------------- fused rope + v-transpose + convt(w_proj) --------------------
// All three are independent once the qkv GEMM is done (S0 is dead then).
// Blocks 0..2559: rope, 2560..4607: vt, 4608..5631: convt w_proj -> S0.
__global__ __launch_bounds__(256) void postqkv_kernel(
    const short* __restrict__ qkv, const float* __restrict__ cosp,
    const float* __restrict__ sinp, short* __restrict__ q,
    short* __restrict__ k, short* __restrict__ vout,
    const float* __restrict__ w_proj, short* __restrict__ S0) {
  int bid = blockIdx.x;
  if (bid < 2560) {
    // ---- rope: one thread = 8 rotary pairs (32B), head-uniform waves ----
    int idx = bid * 256 + threadIdx.x;
    int oct = idx & 3;
    int tmp = idx >> 2;
    int t = tmp & 1023;
    int tmp2 = tmp >> 10;  // b*40 + head
    int head = tmp2 % 40;
    int b = tmp2 / 40;
    const short* src = qkv + (size_t)(b * T_ + t) * 3072 + head * 64 + oct * 16;
    short8 v0 = *(const short8*)(src);
    short8 v1 = *(const short8*)(src + 8);
    const float4* cp = (const float4*)(cosp + t * 32 + oct * 8);
    const float4* sp = (const float4*)(sinp + t * 32 + oct * 8);
    float4 c0 = cp[0], c1 = cp[1];
    float4 s0 = sp[0], s1 = sp[1];
    float sc = head < 32 ? 0.125f : 1.0f;
    float cc[8] = {c0.x, c0.y, c0.z, c0.w, c1.x, c1.y, c1.z, c1.w};
    float ss[8] = {s0.x, s0.y, s0.z, s0.w, s1.x, s1.y, s1.z, s1.w};
    unsigned w[8];
#pragma unroll
    for (int p = 0; p < 8; ++p) {
      float e = b2f(p < 4 ? v0[2 * p] : v1[2 * (p - 4)]);
      float o = b2f(p < 4 ? v0[2 * p + 1] : v1[2 * (p - 4) + 1]);
      w[p] = pk2((e * cc[p] - o * ss[p]) * sc, (e * ss[p] + o * cc[p]) * sc);
    }
    short* dst = (head < 32)
        ? q + ((size_t)(b * 32 + head) * 1024 + t) * 64 + oct * 16
        : k + ((size_t)(b * 8 + head - 32) * 1024 + t) * 64 + oct * 16;
    ((uint4*)dst)[0] = make_uint4(w[0], w[1], w[2], w[3]);
    ((uint4*)dst)[1] = make_uint4(w[4], w[5], w[6], w[7]);
  } else if (bid < 4608) {
    // ---- vt: qkv v-heads [b][t][3072] -> vt[bg][d][t] ----
    __shared__ short tbuf[32][33];
    int vid = bid - 2560;
    int bg = vid >> 6;
    int rest = vid & 63;
    int d0 = (rest >> 5) * 32;
    int t0 = (rest & 31) * 32;
    int b = bg >> 3, g = bg & 7;
    int tx = threadIdx.x & 31, ty = threadIdx.x >> 5;
    const short* src = qkv + (size_t)b * T_ * 3072 + (40 + g) * 64;
    short* dst = vout + (size_t)bg * T_ * HD_;
#pragma unroll
    for (int j = 0; j < 4; ++j)
      tbuf[ty + j * 8][tx] = src[(size_t)(t0 + ty + j * 8) * 3072 + d0 + tx];
    __syncthreads();
#pragma unroll
    for (int j = 0; j < 4; ++j)
      dst[(size_t)(d0 + ty + j * 8) * T_ + t0 + tx] = tbuf[tx][ty + j * 8];
  } else {
    // ---- convt: w_proj [2048][2048] fp32 -> S0 [2048][2048] bf16^T ----
    int lid = bid - 4608;
    convt_body(w_proj, S0, 2048, 2048, (lid & 31) * 64, (lid >> 5) * 64);
  }
}

// ---------------- Flash attention (GQA, causal), S^T/O^T formulation ----------
// T13 defer-max + T5 setprio; tree-associated reductions.
__global__ __launch_bounds__(256) void attn_kernel(
    const short* __restrict__ q, const short* __restrict__ k,
    const short* __restrict__ vt, short* __restrict__ y) {
  __shared__ __align__(16) short P[4][1024];  // per-wave 16 q x 64 key bf16
  int bx = blockIdx.x, h = blockIdx.y, b = blockIdx.z;
  int lane = threadIdx.x & 63, wave = threadIdx.x >> 6;
  int quad = lane >> 4, l16 = lane & 15;
  int g = h >> 2;
  const short* qp = q + (size_t)(b * H_ + h) * T_ * HD_;
  const short* kp = k + (size_t)(b * HKV_ + g) * T_ * HD_;
  const short* vp = vt + (size_t)(b * HKV_ + g) * T_ * HD_;  // [d][t]
  short* Pw = &P[wave][0];
  int sw = (l16 & 7) << 1;  // even xor keeps b128 pairing + 16B alignment
#pragma unroll 1
  for (int half = 0; half < 2; ++half) {
    int tb = half ? (15 - bx) : bx;
    int q0w = tb * 64 + wave * 16;
    int qidx = q0w + l16;
    short8 qf0 = *(const short8*)(qp + (size_t)(q0w + l16) * HD_ + quad * 8);
    short8 qf1 = *(const short8*)(qp + (size_t)(q0w + l16) * HD_ + 32 + quad * 8);
    floatx4 acc[4] = {};
    float m = -1e30f, l = 0.f;
    for (int k0 = 0; k0 <= q0w; k0 += 64) {
      floatx4 st[4];
      __builtin_amdgcn_s_setprio(1);
#pragma unroll
      for (int kt = 0; kt < 4; ++kt) {
        floatx4 z = {0.f, 0.f, 0.f, 0.f};
        const short* kb = kp + (size_t)(k0 + kt * 16 + l16) * HD_;
        short8 kf0 = *(const short8*)(kb + quad * 8);
        short8 kf1 = *(const short8*)(kb + 32 + quad * 8);
        z = __builtin_amdgcn_mfma_f32_16x16x32_bf16(kf0, qf0, z, 0, 0, 0);
        z = __builtin_amdgcn_mfma_f32_16x16x32_bf16(kf1, qf1, z, 0, 0, 0);
        st[kt] = z;
      }
      __builtin_amdgcn_s_setprio(0);
      if (k0 + 64 > q0w) {  // only the diagonal iteration needs the causal mask
#pragma unroll
        for (int kt = 0; kt < 4; ++kt)
#pragma unroll
          for (int r = 0; r < 4; ++r)
            if (k0 + kt * 16 + quad * 4 + r > qidx) st[kt][r] = -1e30f;
      }
      float mk[4];
#pragma unroll
      for (int kt = 0; kt < 4; ++kt)
        mk[kt] = fmaxf(fmaxf(st[kt][0], st[kt][1]),
                       fmaxf(st[kt][2], st[kt][3]));
      float mloc = fmaxf(fmaxf(mk[0], mk[1]), fmaxf(mk[2], mk[3]));
      mloc = fmaxf(mloc, __shfl_xor(mloc, 16, 64));
      mloc = fmaxf(mloc, __shfl_xor(mloc, 32, 64));
      if (!__all(mloc <= m + 8.0f)) {  // T13: rescale only on real max growth
        float mn = fmaxf(m, mloc);
        float alpha = __expf(m - mn);
        m = mn;
        l *= alpha;
#pragma unroll
        for (int mt = 0; mt < 4; ++mt)
#pragma unroll
          for (int r = 0; r < 4; ++r) acc[mt][r] *= alpha;
      }
      float sk[4];
#pragma unroll
      for (int kt = 0; kt < 4; ++kt) {
        float p0 = __expf(st[kt][0] - m);
        float p1 = __expf(st[kt][1] - m);
        float p2 = __expf(st[kt][2] - m);
        float p3 = __expf(st[kt][3] - m);
        st[kt][0] = p0; st[kt][1] = p1; st[kt][2] = p2; st[kt][3] = p3;
        sk[kt] = (p0 + p1) + (p2 + p3);
      }
      float rsum = (sk[0] + sk[1]) + (sk[2] + sk[3]);
      rsum += __shfl_xor(rsum, 16, 64);
      rsum += __shfl_xor(rsum, 32, 64);
      l += rsum;
      // P^T -> LDS as P[q][key], 4 consecutive keys packed per b64 write
#pragma unroll
      for (int kt = 0; kt < 4; ++kt) {
        int hc = (kt * 4 + quad) ^ sw;
        *(uint2*)(Pw + l16 * 64 + hc * 4) =
            make_uint2(pk2(st[kt][0], st[kt][1]), pk2(st[kt][2], st[kt][3]));
      }
      __builtin_amdgcn_s_setprio(1);
#pragma unroll
      for (int chunk = 0; chunk < 2; ++chunk) {
        int hc = (chunk * 8 + quad * 2) ^ sw;
        short8 pf = *(const short8*)(Pw + l16 * 64 + hc * 4);
#pragma unroll
        for (int mt = 0; mt < 4; ++mt) {
          short8 vf = *(const short8*)(vp + (size_t)(mt * 16 + l16) * T_ +
                                       k0 + chunk * 32 + quad * 8);
          acc[mt] =
              __builtin_amdgcn_mfma_f32_16x16x32_bf16(vf, pf, acc[mt], 0, 0, 0);
        }
      }
      __builtin_amdgcn_s_setprio(0);
    }
    // epilogue: O^T/l -> LDS transpose (wave-private) -> coalesced 16B stores
    float inv = 1.0f / l;
#pragma unroll
    for (int mt = 0; mt < 4; ++mt) {
      int hc = (mt * 4 + quad) ^ sw;  // d chunk = mt*16 + quad*4
      *(uint2*)(Pw + l16 * 64 + hc * 4) =
          make_uint2(pk2(acc[mt][0] * inv, acc[mt][1] * inv),
                     pk2(acc[mt][2] * inv, acc[mt][3] * inv));
    }
    uint2 o0 = *(uint2*)(Pw + l16 * 64 + (((quad * 4 + 0) ^ sw) * 4));
    uint2 o1 = *(uint2*)(Pw + l16 * 64 + (((quad * 4 + 1) ^ sw) * 4));
    uint2 o2 = *(uint2*)(Pw + l16 * 64 + (((quad * 4 + 2) ^ sw) * 4));
    uint2 o3 = *(uint2*)(Pw + l16 * 64 + (((quad * 4 + 3) ^ sw) * 4));
    uint4* dst =
        (uint4*)(y + (size_t)(b * T_ + q0w + l16) * C_ + h * 64 + quad * 16);
    dst[0] = make_uint4(o0.x, o0.y, o1.x, o1.y);
    dst[1] = make_uint4(o2.x, o2.y, o3.x, o3.y);
  }
}

extern "C" void kernel_launch(void* const* d_in, const int* in_sizes, int n_in,
                              void* d_out, int out_size, void* d_ws, size_t ws_size,
                              hipStream_t stream) {
  const float* x = (const float*)d_in[0];
  const float* cosp = (const float*)d_in[1];
  const float* sinp = (const float*)d_in[2];
  const float* w_attn = (const float*)d_in[3];
  const float* w_proj = (const float*)d_in[4];
  const float* w_gate = (const float*)d_in[5];
  const float* w_up = (const float*)d_in[6];
  const float* w_down = (const float*)d_in[7];
  const float* scale1 = (const float*)d_in[8];
  const float* scale2 = (const float*)d_in[9];
  float* out = (float*)d_out;
  char* ws = (char*)d_ws;

  // workspace layout (bytes), peak 113,246,208:
  short* S1 = (short*)(ws + 0);            // 23,068,672  wt_gate -> wt_down
  short* S2 = (short*)(ws + 23068672);     // 23,068,672  wt_up
  short* hbuf = (short*)(ws + 46137344);   // 16,777,216  h -> q -> h2
  short* S0 = (short*)(ws + 62914560);     // 12,582,912  wt_attn -> wt_proj
  short* qkv = (short*)(ws + 75497472);    // 25,165,824  qkv -> y
  short* kbuf = (short*)(ws + 100663296);  //  4,194,304
  short* vtbuf = (short*)(ws + 109051904); //  4,194,304  v transposed [bg][d][t]
  short* act = (short*)(ws + 62914560);    // 46,137,344  over S0+qkv+k (dead)

  convt3_kernel<<<7168, 256, 0, stream>>>(w_attn, w_gate, w_up, S0, S1, S2);
  rmsnorm_kernel<<<4096, 256, 0, stream>>>(x, scale1, hbuf);
  gemm128_kernel<0><<<dim3(3072 / 128, 4096 / 128), 256, 0, stream>>>(
      hbuf, S0, qkv, nullptr, 4096, 3072, 2048);
  postqkv_kernel<<<5632, 256, 0, stream>>>(qkv, cosp, sinp, hbuf, kbuf, vtbuf,
                                           w_proj, S0);
  attn_kernel<<<dim3(8, 32, 4), 256, 0, stream>>>(hbuf, kbuf, vtbuf, qkv);
  gemm128_kernel<1><<<dim3(2048 / 128, 4096 / 128), 256, 0, stream>>>(
      qkv, S0, out, x, 4096, 2048, 2048);
  rmsnorm_kernel<<<4096, 256, 0, stream>>>(out, scale2, hbuf);
  gateup_kernel<<<dim3(5632 / 64, 4096 / 128), 256, 0, stream>>>(hbuf, S1, S2, act, 2048);
  convt_kernel<<<dim3(2048 / 64, 5632 / 64), 256, 0, stream>>>(w_down, S1, 5632, 2048);
  gemm128_kernel<1><<<dim3(2048 / 128, 4096 / 128), 256, 0, stream>>>(
      act, S1, out, out, 4096, 2048, 5632);
}